// Round 7
// baseline (164.023 us; speedup 1.0000x reference)
//
#include <hip/hip_runtime.h>
#include <hip/hip_bf16.h>

#define NDIM 64
#define BP   72      // bf16 LDS pitch (setup kernel only)
#define DT_  0.01f
#define NTERM 7

typedef __attribute__((ext_vector_type(8)))  short bf16x8;
typedef __attribute__((ext_vector_type(16))) float f32x16;

struct Frag { bf16x8 f[4]; };

// ---------------- bf16 helpers ----------------

__device__ __forceinline__ unsigned short f2b(float x) {
    __hip_bfloat16 h = __float2bfloat16(x);          // RTNE
    return __builtin_bit_cast(unsigned short, h);
}
__device__ __forceinline__ float b2f(unsigned short u) {
    unsigned int v = (unsigned int)u << 16;
    return __builtin_bit_cast(float, v);
}
__device__ __forceinline__ unsigned int f2b2(float lo, float hi) {
    return (unsigned int)f2b(lo) | ((unsigned int)f2b(hi) << 16);
}

// half-wave lane swap: a.hi-lanes <-> b.lo-lanes (v_permlane32_swap_b32)
__device__ __forceinline__ void plswap(unsigned int& a, unsigned int& b) {
    asm("v_permlane32_swap_b32 %0, %1" : "+v"(a), "+v"(b));
}

// ---------------- fragment helpers (32x32x16 MFMA) ----------------
// A/B frag: lane holds M[rb + (lane&31)][j*16 + (lane>>5)*8 + 0..7]  (one b128)
// C/D slot r: row = rb + (r&3) + 8*(r>>2) + 4*(lane>>5), col = cb + (lane&31)

__device__ __forceinline__ bf16x8 ldfrag(const unsigned short* M, int rb, int j, int ln, int hq) {
    return *(const bf16x8*)&M[(rb + ln) * BP + j * 16 + hq * 8];
}

// operator B-frags (rows cw+ln) from bf16 global, pitch 64
__device__ __forceinline__ void ldg_op(Frag& F, const unsigned short* __restrict__ p,
                                       int ln, int hq, int cw) {
#pragma unroll
    for (int j = 0; j < 4; ++j)
        F.f[j] = *(const bf16x8*)&p[(cw + ln) * 64 + j * 16 + hq * 8];
}

// operator B-frags from LDS (pitch BP)
__device__ __forceinline__ void ldsF(Frag& F, const unsigned short* p, int ln, int hq, int cw) {
#pragma unroll
    for (int j = 0; j < 4; ++j)
        F.f[j] = *(const bf16x8*)&p[(cw + ln) * BP + j * 16 + hq * 8];
}

// operator B-frags straight from fp32 global (rows cw+ln), cast to bf16
__device__ __forceinline__ void ldg_opF32(Frag& F, const float* __restrict__ P,
                                          int ln, int hq, int cw) {
    const int n = cw + ln;
#pragma unroll
    for (int j = 0; j < 4; ++j) {
        const float* q = &P[n * 64 + j * 16 + hq * 8];
        float4 u = *(const float4*)q;
        float4 v = *(const float4*)(q + 4);
        uint4 o;
        o.x = f2b2(u.x, u.y); o.y = f2b2(u.z, u.w);
        o.z = f2b2(v.x, v.y); o.w = f2b2(v.z, v.w);
        F.f[j] = __builtin_bit_cast(bf16x8, o);
    }
}

// W-frags: rows cw+ln of W = I - Uh (fp32 global, setup only)
__device__ __forceinline__ void ldWfrag(Frag& F, const float* __restrict__ Uh,
                                        int ln, int hq, int cw) {
    const int n = cw + ln;
#pragma unroll
    for (int j = 0; j < 4; ++j) {
        const int k0 = j * 16 + hq * 8;
        const float* q = &Uh[n * 64 + k0];
        float4 u = *(const float4*)q;
        float4 v = *(const float4*)(q + 4);
        float wv[8] = {-u.x, -u.y, -u.z, -u.w, -v.x, -v.y, -v.z, -v.w};
#pragma unroll
        for (int e = 0; e < 8; ++e)
            if (n == k0 + e) wv[e] += 1.f;
        uint4 o;
        o.x = f2b2(wv[0], wv[1]); o.y = f2b2(wv[2], wv[3]);
        o.z = f2b2(wv[4], wv[5]); o.w = f2b2(wv[6], wv[7]);
        F.f[j] = __builtin_bit_cast(bf16x8, o);
    }
}

// C = A @ F^T (A rows rb.. from LDS, F = operator row-frags in regs)  [setup only]
template <bool ACC>
__device__ __forceinline__ void ntg(const unsigned short* A, const Frag& F, f32x16& acc,
                                    int ln, int hq, int rb) {
    if (!ACC) {
#pragma unroll
        for (int r = 0; r < 16; ++r) acc[r] = 0.f;
    }
#pragma unroll
    for (int j = 0; j < 4; ++j)
        acc = __builtin_amdgcn_mfma_f32_32x32x16_bf16(ldfrag(A, rb, j, ln, hq), F.f[j], acc, 0, 0, 0);
}

// C = A @ F^T with A-frags in registers; zero C-input via Z
__device__ __forceinline__ f32x16 ntg_reg(const Frag& A, const Frag& F, const f32x16& Z) {
    f32x16 a = __builtin_amdgcn_mfma_f32_32x32x16_bf16(A.f[0], F.f[0], Z, 0, 0, 0);
#pragma unroll
    for (int j = 1; j < 4; ++j)
        a = __builtin_amdgcn_mfma_f32_32x32x16_bf16(A.f[j], F.f[j], a, 0, 0, 0);
    return a;
}

// non-transposed slot store: slot (row,col) -> LDS[row][col] (scalar; setup only)
__device__ __forceinline__ void stN(unsigned short* D, const f32x16& v,
                                    int ln, int hq, int rw, int cw) {
#pragma unroll
    for (int r = 0; r < 16; ++r) {
        int row = rw + (r & 3) + 8 * (r >> 2) + 4 * hq;
        D[row * BP + (cw + ln)] = f2b(v[r]);
    }
}

// transposed read into slot order (floats; setup only)
__device__ __forceinline__ void ldT(float* r, const unsigned short* S,
                                    int ln, int hq, int rw, int cw) {
#pragma unroll
    for (int g = 0; g < 4; ++g) {
        uint2 u = *(const uint2*)&S[(cw + ln) * BP + rw + 8 * g + 4 * hq];
        unsigned short o[4];
        *(uint2*)o = u;
#pragma unroll
        for (int j = 0; j < 4; ++j) r[4 * g + j] = b2f(o[j]);
    }
}

// emit scaled term to ws row-major: slot(row,col) -> ws[col][row]
__device__ __forceinline__ void emit(unsigned short* __restrict__ g, const f32x16& v, float s,
                                     int ln, int hq, int rw, int cw) {
#pragma unroll
    for (int gq = 0; gq < 4; ++gq) {
        uint2 o;
        o.x = f2b2(s * v[4 * gq + 0], s * v[4 * gq + 1]);
        o.y = f2b2(s * v[4 * gq + 2], s * v[4 * gq + 3]);
        *(uint2*)&g[(cw + ln) * 64 + rw + 8 * gq + 4 * hq] = o;
    }
}

// ---------------- setup: THREE blocks build the 7 dominant sandwich operators --------
// out = sum_t Gt rho Gt^T (sqrt(coef) folded into Gt). ws g[t] = Gt row-major bf16.
// g0=U1(1)  g1,2=U1·L0k(c16)  g3,4=U1·V·Lhj·Uh(c23)  g5,6=L1m·U1(c16)
// blk0: shallow ops g0,g1,g2,g5,g6 (1 barrier). blk1/blk2: 4-stage chain for g3/g4
// (each recomputes V = I+W+W^2 -- duplicate work, removes serial coupling).
// Invariant: LDS buffers hold G^T row-major; ntg(curr, Op-rows) = (Op G)^T slots ->
// stN keeps invariant; emit stores transposed -> row-major G in ws.

__global__ void __launch_bounds__(256) krk_setup(const float* __restrict__ Uh,
                                                 const float* __restrict__ U1,
                                                 const float* __restrict__ L0,
                                                 const float* __restrict__ Lh,
                                                 const float* __restrict__ L1,
                                                 unsigned short* __restrict__ ws) {
    __shared__ unsigned short B[7][NDIM * BP];   // 64512 B

    const int blk = blockIdx.x, tid = threadIdx.x;
    const int lane = tid & 63, w = tid >> 6, ln = lane & 31, hq = lane >> 5;
    const int rw = 32 * (w >> 1), cw = 32 * (w & 1);

    const float c16 = DT_ / 6.f, c23 = 2.f * DT_ / 3.f;
    const float sA = sqrtf(c16);               // g1,g2,g5,g6
    const float sB = sqrtf(c23);               // g3,g4

    // ---- staging (all blocks): B0=Uh^T B1=U1^T B2=L00^T B3=L01^T B4=W B5=W^T ; g0=U1
#pragma unroll
    for (int i = 0; i < 4; ++i) {
        int flat = (tid + i * 256) * 4;
        int r = flat >> 6, c = flat & 63;
        float4 u = *(const float4*)&Uh[flat];
        const float* uf = (const float*)&u;
        float wv[4];
#pragma unroll
        for (int j = 0; j < 4; ++j) wv[j] = ((r == c + j) ? 1.f : 0.f) - uf[j];
#pragma unroll
        for (int j = 0; j < 4; ++j) B[0][(c + j) * BP + r] = f2b(uf[j]);
        uint2 ow; ow.x = f2b2(wv[0], wv[1]); ow.y = f2b2(wv[2], wv[3]);
        *(uint2*)&B[4][r * BP + c] = ow;
#pragma unroll
        for (int j = 0; j < 4; ++j) B[5][(c + j) * BP + r] = f2b(wv[j]);

        float4 p = *(const float4*)&U1[flat];
        const float* pf = (const float*)&p;
#pragma unroll
        for (int j = 0; j < 4; ++j) B[1][(c + j) * BP + r] = f2b(pf[j]);
        uint2 oq; oq.x = f2b2(p.x, p.y); oq.y = f2b2(p.z, p.w);
        if (blk == 0) *(uint2*)&ws[flat] = oq;                // g0 = U1 row-major

        float4 a = *(const float4*)&L0[flat];
        const float* af = (const float*)&a;
#pragma unroll
        for (int j = 0; j < 4; ++j) B[2][(c + j) * BP + r] = f2b(af[j]);
        float4 b = *(const float4*)&L0[4096 + flat];
        const float* bf = (const float*)&b;
#pragma unroll
        for (int j = 0; j < 4; ++j) B[3][(c + j) * BP + r] = f2b(bf[j]);
    }

    Frag FU1, Fa, Fb;
    ldg_opF32(FU1, U1, ln, hq, cw);
    if (blk == 0) {
        ldg_opF32(Fa, L1,        ln, hq, cw);                 // F10
        ldg_opF32(Fb, L1 + 4096, ln, hq, cw);                 // F11
    } else {
        ldWfrag(Fa, Uh, ln, hq, cw);                          // Fw
        ldg_opF32(Fb, (blk == 1) ? Lh : Lh + 4096, ln, hq, cw); // FLhj
    }
    __syncthreads();

    f32x16 e;

    if (blk == 0) {
        // ---- shallow: g1,g2 = U1·L0k ; g5,g6 = L1m·U1
        ntg<false>(B[2], FU1, e, ln, hq, rw); emit(ws + 1 * 4096, e, sA, ln, hq, rw, cw);
        ntg<false>(B[3], FU1, e, ln, hq, rw); emit(ws + 2 * 4096, e, sA, ln, hq, rw, cw);
        ntg<false>(B[1], Fa,  e, ln, hq, rw); emit(ws + 5 * 4096, e, sA, ln, hq, rw, cw);
        ntg<false>(B[1], Fb,  e, ln, hq, rw); emit(ws + 6 * 4096, e, sA, ln, hq, rw, cw);
        return;
    }

    // ---- deep chain (blk 1/2): V -> Y' = Lhj·Uh -> Z' = V·Y' -> g = U1·Z'
    {   // V = I + W + W^2 -> B6 row-major
        f32x16 t0;
        ntg<false>(B[5], Fa, t0, ln, hq, rw);                 // (W^2)^T slots
        float wts[16];
        ldT(wts, B[4], ln, hq, rw, cw);                       // W^T slots
#pragma unroll
        for (int g = 0; g < 4; ++g) {
            float vv[4];
#pragma unroll
            for (int i = 0; i < 4; ++i) {
                int r = 4 * g + i;
                int row = rw + i + 8 * g + 4 * hq;
                vv[i] = ((row == cw + ln) ? 1.f : 0.f) + wts[r] + t0[r];
            }
            uint2 o; o.x = f2b2(vv[0], vv[1]); o.y = f2b2(vv[2], vv[3]);
            *(uint2*)&B[6][(cw + ln) * BP + rw + 8 * g + 4 * hq] = o;
        }
    }
    __syncthreads();

    ntg<false>(B[0], Fb, e, ln, hq, rw); stN(B[2], e, ln, hq, rw, cw);   // (Lhj·Uh)^T
    __syncthreads();

    Frag FV; ldsF(FV, B[6], ln, hq, cw);
    ntg<false>(B[2], FV, e, ln, hq, rw); stN(B[4], e, ln, hq, rw, cw);   // (V·Y')^T
    __syncthreads();

    ntg<false>(B[4], FU1, e, ln, hq, rw);
    emit(ws + (size_t)(blk == 1 ? 3 : 4) * 4096, e, sB, ln, hq, rw, cw); // g3/g4
}

// ---------------- main: 1 matrix per BLOCK (128 thr = 2 waves), terms split 4/3 ------
// wave0: terms 0-3, wave1: terms 4-6. Per term t: T = rho @ Gt^T in regs (GEMM1);
// GEMM1 C-layout gives each lane a column of T = row of T^T; missing hq-half k-elems
// live in lane+-32 -> assembled via f2b2 pack + v_permlane32_swap_b32. GEMM2:
// acc += T^T-frags @ Gt^T = (Gt T)^T. Partial accs combined via 8 KB LDS exchange
// (2 rounds, conflict-free), wave0 stores. Grid 4096 blocks -> 32 waves/CU theoretical.

__global__ void __launch_bounds__(128, 2) krk_main(const float* __restrict__ rho0,
                                                   const unsigned short* __restrict__ ws,
                                                   float* __restrict__ out) {
    __shared__ float xch[2][16][64];   // 8192 B

    const int tid = threadIdx.x;
    const int w = tid >> 6, lane = tid & 63, ln = lane & 31, hq = lane >> 5;

    const float* rho = rho0 + (size_t)blockIdx.x * 4096;

    // A-frags: rho rows, both 32-row blocks (full matrix per wave, 32 VGPR)
    Frag Ar[2];
#pragma unroll
    for (int kb = 0; kb < 2; ++kb)
#pragma unroll
        for (int j = 0; j < 4; ++j) {
            const float* q = &rho[(kb * 32 + ln) * 64 + j * 16 + hq * 8];
            float4 u = *(const float4*)q;
            float4 v = *(const float4*)(q + 4);
            uint4 o;
            o.x = f2b2(u.x, u.y); o.y = f2b2(u.z, u.w);
            o.z = f2b2(v.x, v.y); o.w = f2b2(v.z, v.w);
            Ar[kb].f[j] = __builtin_bit_cast(bf16x8, o);
        }

    f32x16 Z;
#pragma unroll
    for (int r = 0; r < 16; ++r) Z[r] = 0.f;
    f32x16 acc00 = Z, acc01 = Z, acc10 = Z, acc11 = Z;

    const int tbase = w ? 4 : 0;
    const int tcnt  = w ? 3 : 4;

    Frag F[2][2];                    // [parity][c-block rows of G]
    ldg_op(F[0][0], ws + (size_t)tbase * 4096, ln, hq, 0);
    ldg_op(F[0][1], ws + (size_t)tbase * 4096, ln, hq, 32);

#pragma unroll
    for (int i = 0; i < 4; ++i) {
        if (i < tcnt) {
            const int cur = i & 1, nxt = cur ^ 1;
            if (i + 1 < tcnt) {
                ldg_op(F[nxt][0], ws + (size_t)(tbase + i + 1) * 4096, ln, hq, 0);
                ldg_op(F[nxt][1], ws + (size_t)(tbase + i + 1) * 4096, ln, hq, 32);
            }
#pragma unroll
            for (int c = 0; c < 2; ++c) {
                // GEMM1 quadrants (kb, c) -> pack -> swap -> A-frags afr.f[0..3]
                Frag afr;
#pragma unroll
                for (int kb = 0; kb < 2; ++kb) {
                    f32x16 T = ntg_reg(Ar[kb], F[cur][c], Z);
                    unsigned int P[8];
#pragma unroll
                    for (int p = 0; p < 8; ++p) P[p] = f2b2(T[2 * p], T[2 * p + 1]);
                    plswap(P[0], P[2]); plswap(P[1], P[3]);
                    plswap(P[4], P[6]); plswap(P[5], P[7]);
                    uint4 lo; lo.x = P[0]; lo.y = P[1]; lo.z = P[2]; lo.w = P[3];
                    uint4 hi; hi.x = P[4]; hi.y = P[5]; hi.z = P[6]; hi.w = P[7];
                    afr.f[2 * kb]     = __builtin_bit_cast(bf16x8, lo);
                    afr.f[2 * kb + 1] = __builtin_bit_cast(bf16x8, hi);
                }
                // GEMM2: acc[c][J] += afr @ F[J]^T
#pragma unroll
                for (int j = 0; j < 4; ++j) {
                    f32x16& a0 = c ? acc10 : acc00;
                    f32x16& a1 = c ? acc11 : acc01;
                    a0 = __builtin_amdgcn_mfma_f32_32x32x16_bf16(afr.f[j], F[cur][0].f[j], a0, 0, 0, 0);
                    a1 = __builtin_amdgcn_mfma_f32_32x32x16_bf16(afr.f[j], F[cur][1].f[j], a1, 0, 0, 0);
                }
            }
        }
    }

    // ---- combine partials: wave1 -> LDS, wave0 adds (2 rounds x 8 KB)
    if (w == 1) {
#pragma unroll
        for (int r = 0; r < 16; ++r) { xch[0][r][lane] = acc00[r]; xch[1][r][lane] = acc01[r]; }
    }
    __syncthreads();
    if (w == 0) {
#pragma unroll
        for (int r = 0; r < 16; ++r) { acc00[r] += xch[0][r][lane]; acc01[r] += xch[1][r][lane]; }
    }
    __syncthreads();
    if (w == 1) {
#pragma unroll
        for (int r = 0; r < 16; ++r) { xch[0][r][lane] = acc10[r]; xch[1][r][lane] = acc11[r]; }
    }
    __syncthreads();
    if (w == 0) {
#pragma unroll
        for (int r = 0; r < 16; ++r) { acc10[r] += xch[0][r][lane]; acc11[r] += xch[1][r][lane]; }

        // store: acc[I][J] slot (row = I*32 + i + 8g + 4hq, col = J*32 + ln) -> o[col][row]
        float* o = out + (size_t)blockIdx.x * 4096;
#pragma unroll
        for (int I = 0; I < 2; ++I)
#pragma unroll
            for (int J = 0; J < 2; ++J) {
                const f32x16& a = I ? (J ? acc11 : acc10) : (J ? acc01 : acc00);
#pragma unroll
                for (int g = 0; g < 4; ++g) {
                    float4 v;
                    v.x = a[4 * g + 0]; v.y = a[4 * g + 1];
                    v.z = a[4 * g + 2]; v.w = a[4 * g + 3];
                    *(float4*)&o[(J * 32 + ln) * 64 + I * 32 + 8 * g + 4 * hq] = v;
                }
            }
    }
}

// ---------------- host launch ----------------

extern "C" void kernel_launch(void* const* d_in, const int* in_sizes, int n_in,
                              void* d_out, int out_size, void* d_ws, size_t ws_size,
                              hipStream_t stream) {
    const float* rho0 = (const float*)d_in[0];
    const float* Uh   = (const float*)d_in[1];
    const float* U1   = (const float*)d_in[2];
    const float* L0   = (const float*)d_in[3];
    const float* Lh   = (const float*)d_in[4];
    const float* L1   = (const float*)d_in[5];
    float* out = (float*)d_out;
    unsigned short* ws = (unsigned short*)d_ws;   // 7 bf16 64x64 operators = 57344 B

    int Bn = in_sizes[0] / (NDIM * NDIM);         // 4096

    krk_setup<<<3, 256, 0, stream>>>(Uh, U1, L0, Lh, L1, ws);
    krk_main<<<Bn, 128, 0, stream>>>(rho0, ws, out);
}

// Round 8
// 145.330 us; speedup vs baseline: 1.1286x; 1.1286x over previous
//
#include <hip/hip_runtime.h>
#include <hip/hip_bf16.h>

#define NDIM 64
#define BP   72      // bf16 LDS pitch (setup kernel only)
#define DT_  0.01f
#define NTERM 7

typedef __attribute__((ext_vector_type(8)))  short bf16x8;
typedef __attribute__((ext_vector_type(16))) float f32x16;

struct Frag { bf16x8 f[4]; };

// ---------------- bf16 helpers ----------------

__device__ __forceinline__ unsigned short f2b(float x) {
    __hip_bfloat16 h = __float2bfloat16(x);          // RTNE
    return __builtin_bit_cast(unsigned short, h);
}
__device__ __forceinline__ float b2f(unsigned short u) {
    unsigned int v = (unsigned int)u << 16;
    return __builtin_bit_cast(float, v);
}
__device__ __forceinline__ unsigned int f2b2(float lo, float hi) {
    return (unsigned int)f2b(lo) | ((unsigned int)f2b(hi) << 16);
}

// half-wave lane swap: a.hi-lanes <-> b.lo-lanes (v_permlane32_swap_b32)
__device__ __forceinline__ void plswap(unsigned int& a, unsigned int& b) {
    asm("v_permlane32_swap_b32 %0, %1" : "+v"(a), "+v"(b));
}

// ---------------- fragment helpers (32x32x16 MFMA) ----------------
// A/B frag: lane holds M[rb + (lane&31)][j*16 + (lane>>5)*8 + 0..7]  (one b128)
// C/D slot r: row = rb + (r&3) + 8*(r>>2) + 4*(lane>>5), col = cb + (lane&31)

__device__ __forceinline__ bf16x8 ldfrag(const unsigned short* M, int rb, int j, int ln, int hq) {
    return *(const bf16x8*)&M[(rb + ln) * BP + j * 16 + hq * 8];
}

// operator B-frags (rows cw+ln) from bf16 global, pitch 64
__device__ __forceinline__ void ldg_op(Frag& F, const unsigned short* __restrict__ p,
                                       int ln, int hq, int cw) {
#pragma unroll
    for (int j = 0; j < 4; ++j)
        F.f[j] = *(const bf16x8*)&p[(cw + ln) * 64 + j * 16 + hq * 8];
}

// operator B-frags from LDS (pitch BP)
__device__ __forceinline__ void ldsF(Frag& F, const unsigned short* p, int ln, int hq, int cw) {
#pragma unroll
    for (int j = 0; j < 4; ++j)
        F.f[j] = *(const bf16x8*)&p[(cw + ln) * BP + j * 16 + hq * 8];
}

// operator B-frags straight from fp32 global (rows cw+ln), cast to bf16
__device__ __forceinline__ void ldg_opF32(Frag& F, const float* __restrict__ P,
                                          int ln, int hq, int cw) {
    const int n = cw + ln;
#pragma unroll
    for (int j = 0; j < 4; ++j) {
        const float* q = &P[n * 64 + j * 16 + hq * 8];
        float4 u = *(const float4*)q;
        float4 v = *(const float4*)(q + 4);
        uint4 o;
        o.x = f2b2(u.x, u.y); o.y = f2b2(u.z, u.w);
        o.z = f2b2(v.x, v.y); o.w = f2b2(v.z, v.w);
        F.f[j] = __builtin_bit_cast(bf16x8, o);
    }
}

// W-frags: rows cw+ln of W = I - Uh (fp32 global, setup only)
__device__ __forceinline__ void ldWfrag(Frag& F, const float* __restrict__ Uh,
                                        int ln, int hq, int cw) {
    const int n = cw + ln;
#pragma unroll
    for (int j = 0; j < 4; ++j) {
        const int k0 = j * 16 + hq * 8;
        const float* q = &Uh[n * 64 + k0];
        float4 u = *(const float4*)q;
        float4 v = *(const float4*)(q + 4);
        float wv[8] = {-u.x, -u.y, -u.z, -u.w, -v.x, -v.y, -v.z, -v.w};
#pragma unroll
        for (int e = 0; e < 8; ++e)
            if (n == k0 + e) wv[e] += 1.f;
        uint4 o;
        o.x = f2b2(wv[0], wv[1]); o.y = f2b2(wv[2], wv[3]);
        o.z = f2b2(wv[4], wv[5]); o.w = f2b2(wv[6], wv[7]);
        F.f[j] = __builtin_bit_cast(bf16x8, o);
    }
}

// C = A @ F^T (A rows rb.. from LDS, F = operator row-frags in regs)  [setup only]
template <bool ACC>
__device__ __forceinline__ void ntg(const unsigned short* A, const Frag& F, f32x16& acc,
                                    int ln, int hq, int rb) {
    if (!ACC) {
#pragma unroll
        for (int r = 0; r < 16; ++r) acc[r] = 0.f;
    }
#pragma unroll
    for (int j = 0; j < 4; ++j)
        acc = __builtin_amdgcn_mfma_f32_32x32x16_bf16(ldfrag(A, rb, j, ln, hq), F.f[j], acc, 0, 0, 0);
}

// C = A @ F^T with A-frags in registers; zero C-input via Z
__device__ __forceinline__ f32x16 ntg_reg(const Frag& A, const Frag& F, const f32x16& Z) {
    f32x16 a = __builtin_amdgcn_mfma_f32_32x32x16_bf16(A.f[0], F.f[0], Z, 0, 0, 0);
#pragma unroll
    for (int j = 1; j < 4; ++j)
        a = __builtin_amdgcn_mfma_f32_32x32x16_bf16(A.f[j], F.f[j], a, 0, 0, 0);
    return a;
}

// non-transposed slot store: slot (row,col) -> LDS[row][col] (scalar; setup only)
__device__ __forceinline__ void stN(unsigned short* D, const f32x16& v,
                                    int ln, int hq, int rw, int cw) {
#pragma unroll
    for (int r = 0; r < 16; ++r) {
        int row = rw + (r & 3) + 8 * (r >> 2) + 4 * hq;
        D[row * BP + (cw + ln)] = f2b(v[r]);
    }
}

// transposed read into slot order (floats; setup only)
__device__ __forceinline__ void ldT(float* r, const unsigned short* S,
                                    int ln, int hq, int rw, int cw) {
#pragma unroll
    for (int g = 0; g < 4; ++g) {
        uint2 u = *(const uint2*)&S[(cw + ln) * BP + rw + 8 * g + 4 * hq];
        unsigned short o[4];
        *(uint2*)o = u;
#pragma unroll
        for (int j = 0; j < 4; ++j) r[4 * g + j] = b2f(o[j]);
    }
}

// emit scaled term to ws row-major: slot(row,col) -> ws[col][row]
__device__ __forceinline__ void emit(unsigned short* __restrict__ g, const f32x16& v, float s,
                                     int ln, int hq, int rw, int cw) {
#pragma unroll
    for (int gq = 0; gq < 4; ++gq) {
        uint2 o;
        o.x = f2b2(s * v[4 * gq + 0], s * v[4 * gq + 1]);
        o.y = f2b2(s * v[4 * gq + 2], s * v[4 * gq + 3]);
        *(uint2*)&g[(cw + ln) * 64 + rw + 8 * gq + 4 * hq] = o;
    }
}

// ---------------- setup: THREE blocks build the 7 dominant sandwich operators --------
// out = sum_t Gt rho Gt^T (sqrt(coef) folded into Gt). ws g[t] = Gt row-major bf16.
// g0=U1(1)  g1,2=U1·L0k(c16)  g3,4=U1·V·Lhj·Uh(c23)  g5,6=L1m·U1(c16)
// blk0: shallow ops g0,g1,g2,g5,g6. blk1/blk2: 4-stage chain for g3/g4.

__global__ void __launch_bounds__(256) krk_setup(const float* __restrict__ Uh,
                                                 const float* __restrict__ U1,
                                                 const float* __restrict__ L0,
                                                 const float* __restrict__ Lh,
                                                 const float* __restrict__ L1,
                                                 unsigned short* __restrict__ ws) {
    __shared__ unsigned short B[7][NDIM * BP];   // 64512 B

    const int blk = blockIdx.x, tid = threadIdx.x;
    const int lane = tid & 63, w = tid >> 6, ln = lane & 31, hq = lane >> 5;
    const int rw = 32 * (w >> 1), cw = 32 * (w & 1);

    const float c16 = DT_ / 6.f, c23 = 2.f * DT_ / 3.f;
    const float sA = sqrtf(c16);               // g1,g2,g5,g6
    const float sB = sqrtf(c23);               // g3,g4

    // ---- staging (all blocks): B0=Uh^T B1=U1^T B2=L00^T B3=L01^T B4=W B5=W^T ; g0=U1
#pragma unroll
    for (int i = 0; i < 4; ++i) {
        int flat = (tid + i * 256) * 4;
        int r = flat >> 6, c = flat & 63;
        float4 u = *(const float4*)&Uh[flat];
        const float* uf = (const float*)&u;
        float wv[4];
#pragma unroll
        for (int j = 0; j < 4; ++j) wv[j] = ((r == c + j) ? 1.f : 0.f) - uf[j];
#pragma unroll
        for (int j = 0; j < 4; ++j) B[0][(c + j) * BP + r] = f2b(uf[j]);
        uint2 ow; ow.x = f2b2(wv[0], wv[1]); ow.y = f2b2(wv[2], wv[3]);
        *(uint2*)&B[4][r * BP + c] = ow;
#pragma unroll
        for (int j = 0; j < 4; ++j) B[5][(c + j) * BP + r] = f2b(wv[j]);

        float4 p = *(const float4*)&U1[flat];
        const float* pf = (const float*)&p;
#pragma unroll
        for (int j = 0; j < 4; ++j) B[1][(c + j) * BP + r] = f2b(pf[j]);
        uint2 oq; oq.x = f2b2(p.x, p.y); oq.y = f2b2(p.z, p.w);
        if (blk == 0) *(uint2*)&ws[flat] = oq;                // g0 = U1 row-major

        float4 a = *(const float4*)&L0[flat];
        const float* af = (const float*)&a;
#pragma unroll
        for (int j = 0; j < 4; ++j) B[2][(c + j) * BP + r] = f2b(af[j]);
        float4 b = *(const float4*)&L0[4096 + flat];
        const float* bf = (const float*)&b;
#pragma unroll
        for (int j = 0; j < 4; ++j) B[3][(c + j) * BP + r] = f2b(bf[j]);
    }

    Frag FU1, Fa, Fb;
    ldg_opF32(FU1, U1, ln, hq, cw);
    if (blk == 0) {
        ldg_opF32(Fa, L1,        ln, hq, cw);                 // F10
        ldg_opF32(Fb, L1 + 4096, ln, hq, cw);                 // F11
    } else {
        ldWfrag(Fa, Uh, ln, hq, cw);                          // Fw
        ldg_opF32(Fb, (blk == 1) ? Lh : Lh + 4096, ln, hq, cw); // FLhj
    }
    __syncthreads();

    f32x16 e;

    if (blk == 0) {
        // ---- shallow: g1,g2 = U1·L0k ; g5,g6 = L1m·U1
        ntg<false>(B[2], FU1, e, ln, hq, rw); emit(ws + 1 * 4096, e, sA, ln, hq, rw, cw);
        ntg<false>(B[3], FU1, e, ln, hq, rw); emit(ws + 2 * 4096, e, sA, ln, hq, rw, cw);
        ntg<false>(B[1], Fa,  e, ln, hq, rw); emit(ws + 5 * 4096, e, sA, ln, hq, rw, cw);
        ntg<false>(B[1], Fb,  e, ln, hq, rw); emit(ws + 6 * 4096, e, sA, ln, hq, rw, cw);
        return;
    }

    // ---- deep chain (blk 1/2): V -> Y' = Lhj·Uh -> Z' = V·Y' -> g = U1·Z'
    {   // V = I + W + W^2 -> B6 row-major
        f32x16 t0;
        ntg<false>(B[5], Fa, t0, ln, hq, rw);                 // (W^2)^T slots
        float wts[16];
        ldT(wts, B[4], ln, hq, rw, cw);                       // W^T slots
#pragma unroll
        for (int g = 0; g < 4; ++g) {
            float vv[4];
#pragma unroll
            for (int i = 0; i < 4; ++i) {
                int r = 4 * g + i;
                int row = rw + i + 8 * g + 4 * hq;
                vv[i] = ((row == cw + ln) ? 1.f : 0.f) + wts[r] + t0[r];
            }
            uint2 o; o.x = f2b2(vv[0], vv[1]); o.y = f2b2(vv[2], vv[3]);
            *(uint2*)&B[6][(cw + ln) * BP + rw + 8 * g + 4 * hq] = o;
        }
    }
    __syncthreads();

    ntg<false>(B[0], Fb, e, ln, hq, rw); stN(B[2], e, ln, hq, rw, cw);   // (Lhj·Uh)^T
    __syncthreads();

    Frag FV; ldsF(FV, B[6], ln, hq, cw);
    ntg<false>(B[2], FV, e, ln, hq, rw); stN(B[4], e, ln, hq, rw, cw);   // (V·Y')^T
    __syncthreads();

    ntg<false>(B[4], FU1, e, ln, hq, rw);
    emit(ws + (size_t)(blk == 1 ? 3 : 4) * 4096, e, sB, ln, hq, rw, cw); // g3/g4
}

// ---------------- main: 2 matrices per WAVE, zero LDS, zero barriers ----------------
// Per term t, per matrix m: T = rho @ Gt^T in regs (GEMM1); GEMM1 C-layout gives each
// lane a column of T; hq-half k-elems assembled via f2b2 pack + v_permlane32_swap_b32.
// GEMM2 quadrants: out symmetric -> compute only a00 (c0·F0), a01 (c0·F1), a11 (c1·F1);
// quadrant (1,0) = a01 stored R6-transposed, quadrant (0,1) = a01 stored direct
// (wave-coalesced dword rows). 2 mats/wave = ~6 indep chains/SIMD at 2 waves/SIMD
// (Ar 64 + F 32 + temps VGPR, 96 AGPR acc; launch_bounds(256,2) caps at 256 total).

__global__ void __launch_bounds__(256, 2) krk_main(const float* __restrict__ rho0,
                                                   const unsigned short* __restrict__ ws,
                                                   float* __restrict__ out) {
    const int tid = threadIdx.x;
    const int w = tid >> 6, lane = tid & 63, ln = lane & 31, hq = lane >> 5;

    const int mat0 = 8 * blockIdx.x + 2 * w;

    // A-frags: rho rows, both 32-row blocks, for both matrices (64 VGPR)
    Frag Ar[2][2];
#pragma unroll
    for (int m = 0; m < 2; ++m) {
        const float* rho = rho0 + (size_t)(mat0 + m) * 4096;
#pragma unroll
        for (int kb = 0; kb < 2; ++kb)
#pragma unroll
            for (int j = 0; j < 4; ++j) {
                const float* q = &rho[(kb * 32 + ln) * 64 + j * 16 + hq * 8];
                float4 u = *(const float4*)q;
                float4 v = *(const float4*)(q + 4);
                uint4 o;
                o.x = f2b2(u.x, u.y); o.y = f2b2(u.z, u.w);
                o.z = f2b2(v.x, v.y); o.w = f2b2(v.z, v.w);
                Ar[m][kb].f[j] = __builtin_bit_cast(bf16x8, o);
            }
    }

    f32x16 Z;
#pragma unroll
    for (int r = 0; r < 16; ++r) Z[r] = 0.f;
    f32x16 a00[2] = {Z, Z}, a01[2] = {Z, Z}, a11[2] = {Z, Z};

#pragma unroll
    for (int t = 0; t < NTERM; ++t) {
        Frag F0, F1;
        ldg_op(F0, ws + (size_t)t * 4096, ln, hq, 0);
        ldg_op(F1, ws + (size_t)t * 4096, ln, hq, 32);
#pragma unroll
        for (int m = 0; m < 2; ++m) {
            // ---- c = 0: afr = rows of T^T for cols 0-31
            {
                Frag afr;
#pragma unroll
                for (int kb = 0; kb < 2; ++kb) {
                    f32x16 T = ntg_reg(Ar[m][kb], F0, Z);
                    unsigned int P[8];
#pragma unroll
                    for (int p = 0; p < 8; ++p) P[p] = f2b2(T[2 * p], T[2 * p + 1]);
                    plswap(P[0], P[2]); plswap(P[1], P[3]);
                    plswap(P[4], P[6]); plswap(P[5], P[7]);
                    uint4 lo; lo.x = P[0]; lo.y = P[1]; lo.z = P[2]; lo.w = P[3];
                    uint4 hi; hi.x = P[4]; hi.y = P[5]; hi.z = P[6]; hi.w = P[7];
                    afr.f[2 * kb]     = __builtin_bit_cast(bf16x8, lo);
                    afr.f[2 * kb + 1] = __builtin_bit_cast(bf16x8, hi);
                }
#pragma unroll
                for (int j = 0; j < 4; ++j) {
                    a00[m] = __builtin_amdgcn_mfma_f32_32x32x16_bf16(afr.f[j], F0.f[j], a00[m], 0, 0, 0);
                    a01[m] = __builtin_amdgcn_mfma_f32_32x32x16_bf16(afr.f[j], F1.f[j], a01[m], 0, 0, 0);
                }
            }
            // ---- c = 1: afr = rows of T^T for cols 32-63 ; only a11 needed
            {
                Frag afr;
#pragma unroll
                for (int kb = 0; kb < 2; ++kb) {
                    f32x16 T = ntg_reg(Ar[m][kb], F1, Z);
                    unsigned int P[8];
#pragma unroll
                    for (int p = 0; p < 8; ++p) P[p] = f2b2(T[2 * p], T[2 * p + 1]);
                    plswap(P[0], P[2]); plswap(P[1], P[3]);
                    plswap(P[4], P[6]); plswap(P[5], P[7]);
                    uint4 lo; lo.x = P[0]; lo.y = P[1]; lo.z = P[2]; lo.w = P[3];
                    uint4 hi; hi.x = P[4]; hi.y = P[5]; hi.z = P[6]; hi.w = P[7];
                    afr.f[2 * kb]     = __builtin_bit_cast(bf16x8, lo);
                    afr.f[2 * kb + 1] = __builtin_bit_cast(bf16x8, hi);
                }
#pragma unroll
                for (int j = 0; j < 4; ++j)
                    a11[m] = __builtin_amdgcn_mfma_f32_32x32x16_bf16(afr.f[j], F1.f[j], a11[m], 0, 0, 0);
            }
        }
    }

    // ---- stores
#pragma unroll
    for (int m = 0; m < 2; ++m) {
        float* o = out + (size_t)(mat0 + m) * 4096;
        // (0,0): slot (r,c) -> o[c][r]
#pragma unroll
        for (int g = 0; g < 4; ++g) {
            float4 v;
            v.x = a00[m][4 * g + 0]; v.y = a00[m][4 * g + 1];
            v.z = a00[m][4 * g + 2]; v.w = a00[m][4 * g + 3];
            *(float4*)&o[ln * 64 + 8 * g + 4 * hq] = v;
        }
        // (1,1): slot (32+r, 32+c) -> o[32+c][32+r]
#pragma unroll
        for (int g = 0; g < 4; ++g) {
            float4 v;
            v.x = a11[m][4 * g + 0]; v.y = a11[m][4 * g + 1];
            v.z = a11[m][4 * g + 2]; v.w = a11[m][4 * g + 3];
            *(float4*)&o[(32 + ln) * 64 + 32 + 8 * g + 4 * hq] = v;
        }
        // a01 slot (r, 32+c): transposed -> o[32+c][r]  (fills rows 32-63, cols 0-31)
#pragma unroll
        for (int g = 0; g < 4; ++g) {
            float4 v;
            v.x = a01[m][4 * g + 0]; v.y = a01[m][4 * g + 1];
            v.z = a01[m][4 * g + 2]; v.w = a01[m][4 * g + 3];
            *(float4*)&o[(32 + ln) * 64 + 8 * g + 4 * hq] = v;
        }
        // a01 direct (symmetry fill): o[r][32+c]  (rows 0-31, cols 32-63; wave-coalesced)
#pragma unroll
        for (int e = 0; e < 16; ++e) {
            int row = (e & 3) + 8 * (e >> 2) + 4 * hq;
            o[row * 64 + 32 + ln] = a01[m][e];
        }
    }
}

// ---------------- host launch ----------------

extern "C" void kernel_launch(void* const* d_in, const int* in_sizes, int n_in,
                              void* d_out, int out_size, void* d_ws, size_t ws_size,
                              hipStream_t stream) {
    const float* rho0 = (const float*)d_in[0];
    const float* Uh   = (const float*)d_in[1];
    const float* U1   = (const float*)d_in[2];
    const float* L0   = (const float*)d_in[3];
    const float* Lh   = (const float*)d_in[4];
    const float* L1   = (const float*)d_in[5];
    float* out = (float*)d_out;
    unsigned short* ws = (unsigned short*)d_ws;   // 7 bf16 64x64 operators = 57344 B

    int Bn = in_sizes[0] / (NDIM * NDIM);         // 4096

    krk_setup<<<3, 256, 0, stream>>>(Uh, U1, L0, Lh, L1, ws);
    krk_main<<<Bn / 8, 256, 0, stream>>>(rho0, ws, out);
}